// Round 10
// baseline (1030.020 us; speedup 1.0000x reference)
//
#include <hip/hip_runtime.h>
#include <hip/hip_bf16.h>

// ChebConv GNN, N=100000, E=1600000, HID=128, K=4.
// R16: grid-stride persistent props. R14b counters showed OccupancyPercent 38%
//      on the gather kernels: 25000 micro-blocks (~3us each) -> ~98 rounds/CU
//      of block churn starving wave slots. Latency model: rate = waves x depth
//      x 64B / 600ns; 12 waves -> 2.6 TB/s == observed. Fix: 2048 blocks
//      (8/CU = 32-wave capacity), each wave strides over nodes. Same body,
//      wave-uniform records (saddr loads) preserved, BN coeffs hoisted.
//      fillpad frozen at R8 floor; zero-padded edge lists (R15) kept.

#define HID 128
#define NEG 0.01f
#define BN_EPS 1e-5f
#define L2_EPS 1e-12f
#define CAP 64   // ints per node bucket: [count, src0..src62]
#define PGRID 2048  // persistent prop grid: 8 blocks/CU x 256 CU

typedef __attribute__((ext_vector_type(8))) short short8;
typedef __attribute__((ext_vector_type(4))) float floatx4;

__device__ __forceinline__ short f2bf(float f) {
    unsigned u = __float_as_uint(f);
    return (short)((u + 0x7fffu + ((u >> 16) & 1u)) >> 16);
}
__device__ __forceinline__ unsigned pack2bf(float x, float y) {
    return (unsigned)(unsigned short)f2bf(x) | ((unsigned)(unsigned short)f2bf(y) << 16);
}
__device__ __forceinline__ float bflo(unsigned u) { return __uint_as_float(u << 16); }
__device__ __forceinline__ float bfhi(unsigned u) { return __uint_as_float(u & 0xffff0000u); }
__device__ __forceinline__ float bf2f(unsigned short h) { return __uint_as_float((unsigned)h << 16); }

__device__ __forceinline__ float actf(float v, int act) {
    if (act == 0) return v >= 0.f ? v : NEG * v;   // leaky_relu
    if (act == 1) return v > 0.f ? v : 0.f;        // relu
    return v;
}

// ---------------- preprocessing ----------------

// zero bucket counts + BN stat slots + build padded xp [N,4]
__global__ __launch_bounds__(256) void k_zero(int* __restrict__ arr, float* __restrict__ S,
                                              const float* __restrict__ x, float* __restrict__ xp, int N) {
    int i = blockIdx.x * 256 + threadIdx.x;
    if (i < N) {
        arr[(size_t)i * CAP] = 0;
        float4 v;
        v.x = x[(size_t)i * 3 + 0];
        v.y = x[(size_t)i * 3 + 1];
        v.z = x[(size_t)i * 3 + 2];
        v.w = 0.f;
        *(float4*)(xp + (size_t)i * 4) = v;
    }
    if (blockIdx.x == 0) {
        for (int k = threadIdx.x; k < 1024; k += 256) S[k] = 0.f;
    }
}

// one-pass bucket fill: count and slots share lines (R8 layout — measured floor)
__global__ __launch_bounds__(256) void k_fillpad(const int* __restrict__ src, const int* __restrict__ dst,
                                                 int* __restrict__ arr, int E) {
    int e = blockIdx.x * 256 + threadIdx.x;
    if (e >= E) return;
    int d = dst[e];
    int pos = atomicAdd(&arr[(size_t)d * CAP], 1);
    if (pos < CAP - 1) arr[(size_t)d * CAP + 1 + pos] = src[e];
}

// degree -> dinv, clamped count
__global__ __launch_bounds__(256) void k_dinv(const int* __restrict__ arr, float* __restrict__ dinv,
                                              int* __restrict__ cnt, int N) {
    int i = blockIdx.x * 256 + threadIdx.x;
    if (i < N) {
        int d = arr[(size_t)i * CAP];
        dinv[i] = d > 0 ? rsqrtf((float)d) : 0.f;
        cnt[i] = d < CAP - 1 ? d : CAP - 1;
    }
}

// wave per node: slots -> (src, norm) records, zero-padded to multiple of 8;
// also snorm[i] = sum_e w_e
__global__ __launch_bounds__(256) void k_norm(const int* __restrict__ arr, const int* __restrict__ cnt,
                                              const float* __restrict__ dinv, int2* __restrict__ edges,
                                              float* __restrict__ snorm, int N) {
    int node = blockIdx.x * 4 + (threadIdx.x >> 6);
    if (node >= N) return;
    node = __builtin_amdgcn_readfirstlane(node);
    int lane = threadIdx.x & 63;
    int deg = cnt[node];
    int degp = (deg + 7) & ~7;     // <= 64
    float dd = dinv[node];
    int s = (lane < deg) ? arr[(size_t)node * CAP + 1 + lane] : 0;
    float w = (lane < deg) ? -(dinv[s] * dd) : 0.f;
    if (lane < degp) {
        int2 rec;
        rec.x = s;                 // 0 for pads
        rec.y = __float_as_int(w); // 0.f for pads
        edges[(size_t)node * CAP + lane] = rec;
    }
    float sw = w;
    #pragma unroll
    for (int d = 1; d < 64; d <<= 1) sw += __shfl_xor(sw, d);
    if (lane == 0) snorm[node] = sw;
}

// ---------------- propagation ----------------

// F=3 fp32 (stride-4 padded), one thread per node. out = a*prop(T) + b*prev
__global__ __launch_bounds__(256) void k_prop3(const float* __restrict__ T, const float* __restrict__ prev,
                                               float* __restrict__ out, const int* __restrict__ cnt,
                                               const int2* __restrict__ edges,
                                               float a, float b, int N) {
    int i = blockIdx.x * 256 + threadIdx.x;
    if (i >= N) return;
    int deg = cnt[i];
    const int2* eb = edges + (size_t)i * CAP;
    float a0 = 0.f, a1 = 0.f, a2 = 0.f;
    int j = 0;
    for (; j + 4 <= deg; j += 4) {
        int2 r0 = eb[j + 0], r1 = eb[j + 1], r2 = eb[j + 2], r3 = eb[j + 3];
        float4 v0 = *(const float4*)(T + (size_t)r0.x * 4);
        float4 v1 = *(const float4*)(T + (size_t)r1.x * 4);
        float4 v2 = *(const float4*)(T + (size_t)r2.x * 4);
        float4 v3 = *(const float4*)(T + (size_t)r3.x * 4);
        float w0 = __int_as_float(r0.y), w1 = __int_as_float(r1.y);
        float w2 = __int_as_float(r2.y), w3 = __int_as_float(r3.y);
        a0 += w0 * v0.x + w1 * v1.x + w2 * v2.x + w3 * v3.x;
        a1 += w0 * v0.y + w1 * v1.y + w2 * v2.y + w3 * v3.y;
        a2 += w0 * v0.z + w1 * v1.z + w2 * v2.z + w3 * v3.z;
    }
    for (; j < deg; ++j) {
        int2 r = eb[j];
        float w = __int_as_float(r.y);
        float4 v = *(const float4*)(T + (size_t)r.x * 4);
        a0 += w * v.x;
        a1 += w * v.y;
        a2 += w * v.z;
    }
    float r0 = a * a0, r1 = a * a1, r2 = a * a2;
    if (prev) {
        const float* pp = prev + (size_t)i * 4;
        r0 += b * pp[0];
        r1 += b * pp[1];
        r2 += b * pp[2];
    }
    float4 o;
    o.x = r0; o.y = r1; o.z = r2; o.w = 0.f;
    *(float4*)(out + (size_t)i * 4) = o;
}

// prop1 of a layer: T1 = L T0 where T0 = a.act(OUT)+c is NOT materialized yet.
// Grid-stride persistent: each wave loops over nodes. Wave-uniform records
// (saddr loads); BN affine after the sum; T0 side write for own node.
__global__ __launch_bounds__(256) void k_prop1(const unsigned* __restrict__ OUT,
                                               unsigned* __restrict__ T1, unsigned* __restrict__ T0,
                                               const int* __restrict__ cnt, const int2* __restrict__ edges,
                                               const float* __restrict__ snorm, const float* __restrict__ S,
                                               const float* __restrict__ g, const float* __restrict__ be,
                                               int act, float invN, int N) {
    int lane = threadIdx.x & 63;
    // per-lane BN affine coefficients for feats 2*lane, 2*lane+1 (node-independent)
    int f0 = 2 * lane;
    float mu0 = S[f0] * invN, mu1 = S[f0 + 1] * invN;
    float v0 = S[f0 + 128] * invN - mu0 * mu0;
    float v1 = S[f0 + 129] * invN - mu1 * mu1;
    float a0 = g[f0] * rsqrtf(v0 + BN_EPS), a1 = g[f0 + 1] * rsqrtf(v1 + BN_EPS);
    float c0 = be[f0] - mu0 * a0, c1 = be[f0 + 1] - mu1 * a1;

    int wid = blockIdx.x * 4 + (threadIdx.x >> 6);
    int wstride = gridDim.x * 4;
    for (int nd = wid; nd < N; nd += wstride) {
        int node = __builtin_amdgcn_readfirstlane(nd);
        int deg = cnt[node];
        const int2* eb = edges + (size_t)node * CAP;
        float accx = 0.f, accy = 0.f;
        int nb = (deg + 7) >> 3;   // edge lists zero-padded to multiple of 8: no tail
        if (nb > 0) {
            int2 recA[8]; unsigned tA[8];
            int2 recB[8]; unsigned tB[8];
            #pragma unroll
            for (int k = 0; k < 8; ++k) recA[k] = eb[k];
            #pragma unroll
            for (int k = 0; k < 8; ++k) tA[k] = OUT[(size_t)recA[k].x * 64 + lane];
            for (int bi = 1; bi < nb; ++bi) {
                const int2* ebb = eb + bi * 8;
                #pragma unroll
                for (int k = 0; k < 8; ++k) recB[k] = ebb[k];
                #pragma unroll
                for (int k = 0; k < 8; ++k) tB[k] = OUT[(size_t)recB[k].x * 64 + lane];
                #pragma unroll
                for (int k = 0; k < 8; ++k) {
                    float w = __int_as_float(recA[k].y);
                    accx += w * actf(bflo(tA[k]), act);
                    accy += w * actf(bfhi(tA[k]), act);
                }
                #pragma unroll
                for (int k = 0; k < 8; ++k) { recA[k] = recB[k]; tA[k] = tB[k]; }
            }
            #pragma unroll
            for (int k = 0; k < 8; ++k) {
                float w = __int_as_float(recA[k].y);
                accx += w * actf(bflo(tA[k]), act);
                accy += w * actf(bfhi(tA[k]), act);
            }
        }
        float si = snorm[node];
        // T1 = a.acc + s_i.c
        __builtin_nontemporal_store(pack2bf(a0 * accx + si * c0, a1 * accy + si * c1),
                                    &T1[(size_t)node * 64 + lane]);
        // T0 side write
        unsigned h = OUT[(size_t)node * 64 + lane];
        float t0lo = a0 * actf(bflo(h), act) + c0;
        float t0hi = a1 * actf(bfhi(h), act) + c1;
        __builtin_nontemporal_store(pack2bf(t0lo, t0hi), &T0[(size_t)node * 64 + lane]);
    }
}

// F=128 bf16 plain prop (prop2/prop3), grid-stride persistent:
// out = a*gather(T) + b*prev
__global__ __launch_bounds__(256) void k_prop128(const unsigned* __restrict__ T, const unsigned* __restrict__ prev,
                                                 unsigned* __restrict__ out, const int* __restrict__ cnt,
                                                 const int2* __restrict__ edges,
                                                 float a, float b, int N) {
    int lane = threadIdx.x & 63;
    int wid = blockIdx.x * 4 + (threadIdx.x >> 6);
    int wstride = gridDim.x * 4;
    for (int nd = wid; nd < N; nd += wstride) {
        int node = __builtin_amdgcn_readfirstlane(nd);
        int deg = cnt[node];
        const int2* eb = edges + (size_t)node * CAP;
        float accx = 0.f, accy = 0.f;
        int nb = (deg + 7) >> 3;   // padded: no tail
        if (nb > 0) {
            int2 recA[8]; unsigned tA[8];
            int2 recB[8]; unsigned tB[8];
            #pragma unroll
            for (int k = 0; k < 8; ++k) recA[k] = eb[k];
            #pragma unroll
            for (int k = 0; k < 8; ++k) tA[k] = T[(size_t)recA[k].x * 64 + lane];
            for (int bi = 1; bi < nb; ++bi) {
                const int2* ebb = eb + bi * 8;
                #pragma unroll
                for (int k = 0; k < 8; ++k) recB[k] = ebb[k];
                #pragma unroll
                for (int k = 0; k < 8; ++k) tB[k] = T[(size_t)recB[k].x * 64 + lane];
                #pragma unroll
                for (int k = 0; k < 8; ++k) {
                    float w = __int_as_float(recA[k].y);
                    accx += w * bflo(tA[k]);
                    accy += w * bfhi(tA[k]);
                }
                #pragma unroll
                for (int k = 0; k < 8; ++k) { recA[k] = recB[k]; tA[k] = tB[k]; }
            }
            #pragma unroll
            for (int k = 0; k < 8; ++k) {
                float w = __int_as_float(recA[k].y);
                accx += w * bflo(tA[k]);
                accy += w * bfhi(tA[k]);
            }
        }
        float rx = a * accx, ry = a * accy;
        if (prev) {
            unsigned p = __builtin_nontemporal_load(&prev[(size_t)node * 64 + lane]);
            rx += b * bflo(p);
            ry += b * bfhi(p);
        }
        __builtin_nontemporal_store(pack2bf(rx, ry), &out[(size_t)node * 64 + lane]);
    }
}

// ---------------- layer-1 dense (K=12 tiny GEMM), bf16 out + fused BN stats ----------------

__global__ __launch_bounds__(256) void k_gemm1(const float* __restrict__ x, const float* __restrict__ t1,
                                               const float* __restrict__ t2, const float* __restrict__ t3,
                                               const float* __restrict__ W, const float* __restrict__ b,
                                               unsigned short* __restrict__ OUT, float* __restrict__ S,
                                               int npb, int N) {
    __shared__ float Wl[12 * 128];
    __shared__ float bl[128];
    __shared__ float sS[256];
    int tid = threadIdx.x;
    for (int i = tid; i < 1536; i += 256) Wl[i] = W[i];
    if (tid < 128) bl[tid] = b[tid];
    if (tid < 256) sS[tid] = 0.f;
    __syncthreads();
    int f = tid & 127;
    int base = blockIdx.x * npb;
    int end = base + npb < N ? base + npb : N;
    const float* rows[4] = {x, t1, t2, t3};
    float s1 = 0.f, s2 = 0.f;
    for (int node = base + (tid >> 7); node < end; node += 2) {
        float acc = bl[f];
        #pragma unroll
        for (int k = 0; k < 4; ++k) {
            float4 rv = *(const float4*)(rows[k] + (size_t)node * 4);
            acc += rv.x * Wl[(k * 3 + 0) * 128 + f];
            acc += rv.y * Wl[(k * 3 + 1) * 128 + f];
            acc += rv.z * Wl[(k * 3 + 2) * 128 + f];
        }
        unsigned short h = (unsigned short)f2bf(acc);
        OUT[(size_t)node * 128 + f] = h;
        float u = actf(bf2f(h), 0);  // leaky
        s1 += u;
        s2 += u * u;
    }
    atomicAdd(&sS[f], s1);
    atomicAdd(&sS[f + 128], s2);
    __syncthreads();
    if (tid < 256) atomicAdd(&S[tid], sS[tid]);
}

// ---------------- big GEMM: OUT[M,128] = [T0|T1|T2|T3][M,512] @ Wp[512,128] + b ----------------

// pack all 3 layers' W (each [4,128,128] fp32) into bf16 B-fragment order
__global__ __launch_bounds__(256) void k_packW(const float* __restrict__ WA, const float* __restrict__ WB,
                                               const float* __restrict__ WC, short* __restrict__ Wp) {
    int gid = blockIdx.x * 256 + threadIdx.x;  // 0..196607
    int L = gid >> 16;
    int idx = gid & 65535;
    int j = idx & 7;
    int lane = (idx >> 3) & 63;
    int rest = idx >> 9;
    int nt = rest & 7;
    int ks = rest >> 3;
    int kk = ks * 32 + (lane >> 4) * 8 + j;
    int c = nt * 16 + (lane & 15);
    const float* W = (L == 0) ? WA : (L == 1) ? WB : WC;
    Wp[gid] = f2bf(W[(size_t)(kk >> 7) * 16384 + (kk & 127) * 128 + c]);
}

// Weight-resident persistent GEMM (1 block/CU, full 128KB weight in LDS).
// doStats: fused BN stats -> S. doFinal: fused L2-normalize + 128->3 projection
// (skips OUT store, writes fout[N,3]).
__global__ __launch_bounds__(512) void k_gemm512(const short* __restrict__ T0, const short* __restrict__ T1,
                                                 const short* __restrict__ T2, const short* __restrict__ T3,
                                                 const short* __restrict__ Wp, const float* __restrict__ bias,
                                                 unsigned short* __restrict__ OUT, float* __restrict__ S,
                                                 const float* __restrict__ Wrep, const float* __restrict__ brep,
                                                 float* __restrict__ fout,
                                                 int M, int doStats, int doFinal, int act) {
    __shared__ short Wlds[65536];   // 128 KB
    __shared__ float sS[256];
    __shared__ float sW[388];       // Wrep (384) + brep (3)
    int tid = threadIdx.x;
    int lane = tid & 63, wave = tid >> 6;
    if (tid < 256) sS[tid] = 0.f;
    if (doFinal) {
        for (int i = tid; i < 384; i += 512) sW[i] = Wrep[i];
        if (tid < 3) sW[384 + tid] = brep[tid];
    }
    for (int i = tid; i < 8192; i += 512) ((int4*)Wlds)[i] = ((const int4*)Wp)[i];
    __syncthreads();

    int quad = lane >> 4;
    int col0 = lane & 15;
    const short* Ts[4] = {T0, T1, T2, T3};
    float s1[8], s2[8];
    #pragma unroll
    for (int i = 0; i < 8; ++i) { s1[i] = 0.f; s2[i] = 0.f; }

    int nt32 = (M + 31) / 32;
    int stride = gridDim.x * 8;
    for (int t = blockIdx.x * 8 + wave; t < nt32; t += stride) {
        int r0 = t * 32;
        int rowa = r0 + col0;
        int rowb = rowa + 16;
        size_t rb0 = (size_t)(rowa < M ? rowa : M - 1) * 128;
        size_t rb1 = (size_t)(rowb < M ? rowb : M - 1) * 128;
        floatx4 acc0[8], acc1[8];
        #pragma unroll
        for (int i = 0; i < 8; ++i) {
            acc0[i][0] = 0.f; acc0[i][1] = 0.f; acc0[i][2] = 0.f; acc0[i][3] = 0.f;
            acc1[i][0] = 0.f; acc1[i][1] = 0.f; acc1[i][2] = 0.f; acc1[i][3] = 0.f;
        }
        #pragma unroll 4
        for (int ks = 0; ks < 16; ++ks) {
            const short* Tm = Ts[ks >> 2];
            int aoff = (ks & 3) * 32 + quad * 8;
            short8 af0 = *((const short8*)(Tm + rb0 + aoff));
            short8 af1 = *((const short8*)(Tm + rb1 + aoff));
            #pragma unroll
            for (int nt = 0; nt < 8; ++nt) {
                short8 bf = *((const short8*)(Wlds + ((ks * 8 + nt) * 64 + lane) * 8));
                acc0[nt] = __builtin_amdgcn_mfma_f32_16x16x32_bf16(af0, bf, acc0[nt], 0, 0, 0);
                acc1[nt] = __builtin_amdgcn_mfma_f32_16x16x32_bf16(af1, bf, acc1[nt], 0, 0, 0);
            }
        }
        // C/D layout: col = lane&15, row = quad*4 + reg
        if (doFinal) {
            #pragma unroll
            for (int half = 0; half < 2; ++half) {
                #pragma unroll
                for (int rg = 0; rg < 4; ++rg) {
                    int r = r0 + half * 16 + quad * 4 + rg;
                    float sq = 0.f, p0 = 0.f, p1 = 0.f, p2 = 0.f;
                    #pragma unroll
                    for (int nt = 0; nt < 8; ++nt) {
                        int c = nt * 16 + col0;
                        float v = (half ? acc1[nt][rg] : acc0[nt][rg]) + bias[c];
                        sq += v * v;
                        p0 += v * sW[c * 3 + 0];
                        p1 += v * sW[c * 3 + 1];
                        p2 += v * sW[c * 3 + 2];
                    }
                    #pragma unroll
                    for (int d = 1; d < 16; d <<= 1) {
                        sq += __shfl_xor(sq, d);
                        p0 += __shfl_xor(p0, d);
                        p1 += __shfl_xor(p1, d);
                        p2 += __shfl_xor(p2, d);
                    }
                    if (col0 == 0 && r < M) {
                        float inv = 1.f / fmaxf(sqrtf(sq), L2_EPS);
                        fout[r * 3 + 0] = p0 * inv + sW[384];
                        fout[r * 3 + 1] = p1 * inv + sW[385];
                        fout[r * 3 + 2] = p2 * inv + sW[386];
                    }
                }
            }
        } else {
            #pragma unroll
            for (int half = 0; half < 2; ++half) {
                int rbase = r0 + half * 16 + quad * 4;
                #pragma unroll
                for (int nt = 0; nt < 8; ++nt) {
                    int c = nt * 16 + col0;
                    float bv = bias[c];
                    #pragma unroll
                    for (int rg = 0; rg < 4; ++rg) {
                        int r = rbase + rg;
                        if (r < M) {
                            float v = (half ? acc1[nt][rg] : acc0[nt][rg]) + bv;
                            unsigned short h = (unsigned short)f2bf(v);
                            OUT[(size_t)r * 128 + c] = h;
                            float u = actf(bf2f(h), act);
                            s1[nt] += u;
                            s2[nt] += u * u;
                        }
                    }
                }
            }
        }
    }
    if (doStats) {
        #pragma unroll
        for (int nt = 0; nt < 8; ++nt) {
            int c = nt * 16 + col0;
            atomicAdd(&sS[c], s1[nt]);
            atomicAdd(&sS[c + 128], s2[nt]);
        }
        __syncthreads();
        if (tid < 256) atomicAdd(&S[tid], sS[tid]);
    }
}

// ---------------- host ----------------

extern "C" void kernel_launch(void* const* d_in, const int* in_sizes, int n_in,
                              void* d_out, int out_size, void* d_ws, size_t ws_size,
                              hipStream_t stream) {
    const int N = in_sizes[0] / 3;   // 100000
    const int E = in_sizes[1] / 2;   // 1600000

    const float* x    = (const float*)d_in[0];
    const int*   ei   = (const int*)d_in[1];
    const int* esrc = ei;
    const int* edst = ei + E;
    const float* W1 = (const float*)d_in[2];  const float* b1 = (const float*)d_in[3];
    const float* W2 = (const float*)d_in[4];  const float* b2 = (const float*)d_in[5];
    const float* W3 = (const float*)d_in[6];  const float* b3 = (const float*)d_in[7];
    const float* W4 = (const float*)d_in[8];  const float* b4 = (const float*)d_in[9];
    const float* g1 = (const float*)d_in[10]; const float* be1 = (const float*)d_in[11];
    const float* g2 = (const float*)d_in[12]; const float* be2 = (const float*)d_in[13];
    const float* g3 = (const float*)d_in[14]; const float* be3 = (const float*)d_in[15];
    const float* Wrep = (const float*)d_in[16]; const float* brep = (const float*)d_in[17];
    float* out = (float*)d_out;

    char* w = (char*)d_ws;
    size_t off = 0;
    auto alloc = [&](size_t bytes) { size_t o = off; off = (off + bytes + 255) & ~(size_t)255; return o; };
    int*   arr    = (int*)(w + alloc((size_t)N * CAP * 4));      // bucket: [count, srcs...]
    int*   cnt    = (int*)(w + alloc((size_t)N * 4));            // clamped degree
    float* dinv   = (float*)(w + alloc((size_t)N * 4));
    float* snorm  = (float*)(w + alloc((size_t)N * 4));          // sum of norms per node
    int2*  edges  = (int2*)(w + alloc((size_t)N * CAP * 8));     // padded (src,norm)
    short* Wp     = (short*)(w + alloc(3 * 65536 * 2));
    float* S      = (float*)(w + alloc(4 * 256 * 4));            // BN stats: S0..S2
    float* xp     = (float*)(w + alloc((size_t)N * 4 * 4));      // padded x [N,4]
    float* t1f    = (float*)(w + alloc((size_t)N * 4 * 4));
    float* t2f    = (float*)(w + alloc((size_t)N * 4 * 4));
    float* t3f    = (float*)(w + alloc((size_t)N * 4 * 4));
    short* T0     = (short*)(w + alloc((size_t)N * 128 * 2));    // bf16 feature bufs
    short* T1     = (short*)(w + alloc((size_t)N * 128 * 2));
    short* T2     = (short*)(w + alloc((size_t)N * 128 * 2));
    short* T3     = (short*)(w + alloc((size_t)N * 128 * 2));
    unsigned short* OUT = (unsigned short*)(w + alloc((size_t)N * 128 * 2));  // bf16

    int gE = (E + 255) / 256;
    int gN = (N + 255) / 256;
    int gW = (N + 3) / 4;            // wave-per-node (k_norm)
    float invN = 1.f / (float)N;
    int npb = (N + 255) / 256;       // nodes per block for persistent gemm1

    // --- preprocessing: one-pass padded CSR ---
    k_zero<<<gN, 256, 0, stream>>>(arr, S, x, xp, N);
    k_fillpad<<<gE, 256, 0, stream>>>(esrc, edst, arr, E);
    k_dinv<<<gN, 256, 0, stream>>>(arr, dinv, cnt, N);
    k_norm<<<gW, 256, 0, stream>>>(arr, cnt, dinv, edges, snorm, N);
    k_packW<<<768, 256, 0, stream>>>(W2, W3, W4, Wp);

    // --- layer 1 (F_in=3, fp32, stride-4 padded) ---
    k_prop3<<<gN, 256, 0, stream>>>(xp, nullptr, t1f, cnt, edges, 1.f, 0.f, N);
    k_prop3<<<gN, 256, 0, stream>>>(t1f, xp, t2f, cnt, edges, 2.f, -1.f, N);
    k_prop3<<<gN, 256, 0, stream>>>(t2f, t1f, t3f, cnt, edges, 2.f, -1.f, N);
    k_gemm1<<<256, 256, 0, stream>>>(xp, t1f, t2f, t3f, W1, b1, OUT, S, npb, N);

    // --- layers 2..4 ---
    const float* bs[3]  = {b2, b3, b4};
    const float* gs[3]  = {g2, g3, nullptr};
    const float* bes[3] = {be2, be3, nullptr};
    // act applied to the PREVIOUS layer's output when forming T0: leaky, leaky, relu
    int actsIn[3] = {0, 0, 1};
    // act for stats on THIS layer's output: leaky (l=0), relu (l=1)
    int actsOut[3] = {0, 1, 2};

    for (int l = 0; l < 3; ++l) {
        float* Sin = S + (size_t)l * 256;        // stats of previous layer output
        float* Sout = S + (size_t)(l + 1) * 256; // stats accumulated this layer
        const float* gc = (l == 0) ? g1 : gs[l - 1];
        const float* bc = (l == 0) ? be1 : bes[l - 1];
        // prop1: gather OUT (raw), act+affine-after-sum -> T1; side write T0
        k_prop1<<<PGRID, 256, 0, stream>>>((const unsigned*)OUT, (unsigned*)T1, (unsigned*)T0,
                                           cnt, edges, snorm, Sin, gc, bc, actsIn[l], invN, N);
        k_prop128<<<PGRID, 256, 0, stream>>>((const unsigned*)T1, (const unsigned*)T0, (unsigned*)T2,
                                             cnt, edges, 2.f, -1.f, N);
        k_prop128<<<PGRID, 256, 0, stream>>>((const unsigned*)T2, (const unsigned*)T1, (unsigned*)T3,
                                             cnt, edges, 2.f, -1.f, N);
        k_gemm512<<<256, 512, 0, stream>>>(T0, T1, T2, T3, Wp + (size_t)l * 65536, bs[l], OUT, Sout,
                                           Wrep, brep, out, N,
                                           l < 2 ? 1 : 0, l == 2 ? 1 : 0, actsOut[l]);
    }
}

// Round 11
// 1002.267 us; speedup vs baseline: 1.0277x; 1.0277x over previous
//
#include <hip/hip_runtime.h>
#include <hip/hip_bf16.h>

// ChebConv GNN, N=100000, E=1600000, HID=128, K=4.
// R17: revert to R15 exactly (session best, 1007.4us). R16's persistent props
//      regressed (+23us): occupancy-starvation theory was an artifact of
//      R14b's broken variant; 25k-block dispatch rebalances better than an
//      exactly-filled persistent grid. Cost structure now fully bracketed:
//      fillpad ~93us (6-round floor), props ~720us (random 256B-row gather
//      at ~5 TB/s effective; TLP probe R16 and width probe R14 both null),
//      GEMMs ~100us (~520 TF effective). Zero-padded edge lists (R15) kept.

#define HID 128
#define NEG 0.01f
#define BN_EPS 1e-5f
#define L2_EPS 1e-12f
#define CAP 64   // ints per node bucket: [count, src0..src62]

typedef __attribute__((ext_vector_type(8))) short short8;
typedef __attribute__((ext_vector_type(4))) float floatx4;

__device__ __forceinline__ short f2bf(float f) {
    unsigned u = __float_as_uint(f);
    return (short)((u + 0x7fffu + ((u >> 16) & 1u)) >> 16);
}
__device__ __forceinline__ unsigned pack2bf(float x, float y) {
    return (unsigned)(unsigned short)f2bf(x) | ((unsigned)(unsigned short)f2bf(y) << 16);
}
__device__ __forceinline__ float bflo(unsigned u) { return __uint_as_float(u << 16); }
__device__ __forceinline__ float bfhi(unsigned u) { return __uint_as_float(u & 0xffff0000u); }
__device__ __forceinline__ float bf2f(unsigned short h) { return __uint_as_float((unsigned)h << 16); }

__device__ __forceinline__ float actf(float v, int act) {
    if (act == 0) return v >= 0.f ? v : NEG * v;   // leaky_relu
    if (act == 1) return v > 0.f ? v : 0.f;        // relu
    return v;
}

// ---------------- preprocessing ----------------

// zero bucket counts + BN stat slots + build padded xp [N,4]
__global__ __launch_bounds__(256) void k_zero(int* __restrict__ arr, float* __restrict__ S,
                                              const float* __restrict__ x, float* __restrict__ xp, int N) {
    int i = blockIdx.x * 256 + threadIdx.x;
    if (i < N) {
        arr[(size_t)i * CAP] = 0;
        float4 v;
        v.x = x[(size_t)i * 3 + 0];
        v.y = x[(size_t)i * 3 + 1];
        v.z = x[(size_t)i * 3 + 2];
        v.w = 0.f;
        *(float4*)(xp + (size_t)i * 4) = v;
    }
    if (blockIdx.x == 0) {
        for (int k = threadIdx.x; k < 1024; k += 256) S[k] = 0.f;
    }
}

// one-pass bucket fill: count and slots share lines (R8 layout — measured floor)
__global__ __launch_bounds__(256) void k_fillpad(const int* __restrict__ src, const int* __restrict__ dst,
                                                 int* __restrict__ arr, int E) {
    int e = blockIdx.x * 256 + threadIdx.x;
    if (e >= E) return;
    int d = dst[e];
    int pos = atomicAdd(&arr[(size_t)d * CAP], 1);
    if (pos < CAP - 1) arr[(size_t)d * CAP + 1 + pos] = src[e];
}

// degree -> dinv, clamped count
__global__ __launch_bounds__(256) void k_dinv(const int* __restrict__ arr, float* __restrict__ dinv,
                                              int* __restrict__ cnt, int N) {
    int i = blockIdx.x * 256 + threadIdx.x;
    if (i < N) {
        int d = arr[(size_t)i * CAP];
        dinv[i] = d > 0 ? rsqrtf((float)d) : 0.f;
        cnt[i] = d < CAP - 1 ? d : CAP - 1;
    }
}

// wave per node: slots -> (src, norm) records, zero-padded to multiple of 8;
// also snorm[i] = sum_e w_e
__global__ __launch_bounds__(256) void k_norm(const int* __restrict__ arr, const int* __restrict__ cnt,
                                              const float* __restrict__ dinv, int2* __restrict__ edges,
                                              float* __restrict__ snorm, int N) {
    int node = blockIdx.x * 4 + (threadIdx.x >> 6);
    if (node >= N) return;
    node = __builtin_amdgcn_readfirstlane(node);
    int lane = threadIdx.x & 63;
    int deg = cnt[node];
    int degp = (deg + 7) & ~7;     // <= 64
    float dd = dinv[node];
    int s = (lane < deg) ? arr[(size_t)node * CAP + 1 + lane] : 0;
    float w = (lane < deg) ? -(dinv[s] * dd) : 0.f;
    if (lane < degp) {
        int2 rec;
        rec.x = s;                 // 0 for pads
        rec.y = __float_as_int(w); // 0.f for pads
        edges[(size_t)node * CAP + lane] = rec;
    }
    float sw = w;
    #pragma unroll
    for (int d = 1; d < 64; d <<= 1) sw += __shfl_xor(sw, d);
    if (lane == 0) snorm[node] = sw;
}

// ---------------- propagation ----------------

// F=3 fp32 (stride-4 padded), one thread per node. out = a*prop(T) + b*prev
__global__ __launch_bounds__(256) void k_prop3(const float* __restrict__ T, const float* __restrict__ prev,
                                               float* __restrict__ out, const int* __restrict__ cnt,
                                               const int2* __restrict__ edges,
                                               float a, float b, int N) {
    int i = blockIdx.x * 256 + threadIdx.x;
    if (i >= N) return;
    int deg = cnt[i];
    const int2* eb = edges + (size_t)i * CAP;
    float a0 = 0.f, a1 = 0.f, a2 = 0.f;
    int j = 0;
    for (; j + 4 <= deg; j += 4) {
        int2 r0 = eb[j + 0], r1 = eb[j + 1], r2 = eb[j + 2], r3 = eb[j + 3];
        float4 v0 = *(const float4*)(T + (size_t)r0.x * 4);
        float4 v1 = *(const float4*)(T + (size_t)r1.x * 4);
        float4 v2 = *(const float4*)(T + (size_t)r2.x * 4);
        float4 v3 = *(const float4*)(T + (size_t)r3.x * 4);
        float w0 = __int_as_float(r0.y), w1 = __int_as_float(r1.y);
        float w2 = __int_as_float(r2.y), w3 = __int_as_float(r3.y);
        a0 += w0 * v0.x + w1 * v1.x + w2 * v2.x + w3 * v3.x;
        a1 += w0 * v0.y + w1 * v1.y + w2 * v2.y + w3 * v3.y;
        a2 += w0 * v0.z + w1 * v1.z + w2 * v2.z + w3 * v3.z;
    }
    for (; j < deg; ++j) {
        int2 r = eb[j];
        float w = __int_as_float(r.y);
        float4 v = *(const float4*)(T + (size_t)r.x * 4);
        a0 += w * v.x;
        a1 += w * v.y;
        a2 += w * v.z;
    }
    float r0 = a * a0, r1 = a * a1, r2 = a * a2;
    if (prev) {
        const float* pp = prev + (size_t)i * 4;
        r0 += b * pp[0];
        r1 += b * pp[1];
        r2 += b * pp[2];
    }
    float4 o;
    o.x = r0; o.y = r1; o.z = r2; o.w = 0.f;
    *(float4*)(out + (size_t)i * 4) = o;
}

// prop1 of a layer: T1 = L T0 where T0 = a.act(OUT)+c is NOT materialized yet.
// Gathers raw OUT (wave-uniform records -> saddr loads), act per element,
// affine after the sum (a*acc + s_i*c). T0 side write for own node.
__global__ __launch_bounds__(256) void k_prop1(const unsigned* __restrict__ OUT,
                                               unsigned* __restrict__ T1, unsigned* __restrict__ T0,
                                               const int* __restrict__ cnt, const int2* __restrict__ edges,
                                               const float* __restrict__ snorm, const float* __restrict__ S,
                                               const float* __restrict__ g, const float* __restrict__ be,
                                               int act, float invN, int N) {
    int node = blockIdx.x * 4 + (threadIdx.x >> 6);
    if (node >= N) return;
    node = __builtin_amdgcn_readfirstlane(node);
    int lane = threadIdx.x & 63;
    // per-lane BN affine coefficients for feats 2*lane, 2*lane+1
    int f0 = 2 * lane;
    float mu0 = S[f0] * invN, mu1 = S[f0 + 1] * invN;
    float v0 = S[f0 + 128] * invN - mu0 * mu0;
    float v1 = S[f0 + 129] * invN - mu1 * mu1;
    float a0 = g[f0] * rsqrtf(v0 + BN_EPS), a1 = g[f0 + 1] * rsqrtf(v1 + BN_EPS);
    float c0 = be[f0] - mu0 * a0, c1 = be[f0 + 1] - mu1 * a1;

    int deg = cnt[node];
    const int2* eb = edges + (size_t)node * CAP;
    float accx = 0.f, accy = 0.f;
    int nb = (deg + 7) >> 3;   // edge lists zero-padded to multiple of 8: no tail
    if (nb > 0) {
        int2 recA[8]; unsigned tA[8];
        int2 recB[8]; unsigned tB[8];
        #pragma unroll
        for (int k = 0; k < 8; ++k) recA[k] = eb[k];
        #pragma unroll
        for (int k = 0; k < 8; ++k) tA[k] = OUT[(size_t)recA[k].x * 64 + lane];
        for (int bi = 1; bi < nb; ++bi) {
            const int2* ebb = eb + bi * 8;
            #pragma unroll
            for (int k = 0; k < 8; ++k) recB[k] = ebb[k];
            #pragma unroll
            for (int k = 0; k < 8; ++k) tB[k] = OUT[(size_t)recB[k].x * 64 + lane];
            #pragma unroll
            for (int k = 0; k < 8; ++k) {
                float w = __int_as_float(recA[k].y);
                accx += w * actf(bflo(tA[k]), act);
                accy += w * actf(bfhi(tA[k]), act);
            }
            #pragma unroll
            for (int k = 0; k < 8; ++k) { recA[k] = recB[k]; tA[k] = tB[k]; }
        }
        #pragma unroll
        for (int k = 0; k < 8; ++k) {
            float w = __int_as_float(recA[k].y);
            accx += w * actf(bflo(tA[k]), act);
            accy += w * actf(bfhi(tA[k]), act);
        }
    }
    float si = snorm[node];
    // T1 = a.acc + s_i.c
    __builtin_nontemporal_store(pack2bf(a0 * accx + si * c0, a1 * accy + si * c1),
                                &T1[(size_t)node * 64 + lane]);
    // T0 side write
    unsigned h = OUT[(size_t)node * 64 + lane];
    float t0lo = a0 * actf(bflo(h), act) + c0;
    float t0hi = a1 * actf(bfhi(h), act) + c1;
    __builtin_nontemporal_store(pack2bf(t0lo, t0hi), &T0[(size_t)node * 64 + lane]);
}

// F=128 bf16 plain prop (prop2/prop3): out = a*gather(T) + b*prev
__global__ __launch_bounds__(256) void k_prop128(const unsigned* __restrict__ T, const unsigned* __restrict__ prev,
                                                 unsigned* __restrict__ out, const int* __restrict__ cnt,
                                                 const int2* __restrict__ edges,
                                                 float a, float b, int N) {
    int node = blockIdx.x * 4 + (threadIdx.x >> 6);
    if (node >= N) return;
    node = __builtin_amdgcn_readfirstlane(node);
    int lane = threadIdx.x & 63;
    int deg = cnt[node];
    const int2* eb = edges + (size_t)node * CAP;
    float accx = 0.f, accy = 0.f;
    int nb = (deg + 7) >> 3;   // padded: no tail
    if (nb > 0) {
        int2 recA[8]; unsigned tA[8];
        int2 recB[8]; unsigned tB[8];
        #pragma unroll
        for (int k = 0; k < 8; ++k) recA[k] = eb[k];
        #pragma unroll
        for (int k = 0; k < 8; ++k) tA[k] = T[(size_t)recA[k].x * 64 + lane];
        for (int bi = 1; bi < nb; ++bi) {
            const int2* ebb = eb + bi * 8;
            #pragma unroll
            for (int k = 0; k < 8; ++k) recB[k] = ebb[k];
            #pragma unroll
            for (int k = 0; k < 8; ++k) tB[k] = T[(size_t)recB[k].x * 64 + lane];
            #pragma unroll
            for (int k = 0; k < 8; ++k) {
                float w = __int_as_float(recA[k].y);
                accx += w * bflo(tA[k]);
                accy += w * bfhi(tA[k]);
            }
            #pragma unroll
            for (int k = 0; k < 8; ++k) { recA[k] = recB[k]; tA[k] = tB[k]; }
        }
        #pragma unroll
        for (int k = 0; k < 8; ++k) {
            float w = __int_as_float(recA[k].y);
            accx += w * bflo(tA[k]);
            accy += w * bfhi(tA[k]);
        }
    }
    float rx = a * accx, ry = a * accy;
    if (prev) {
        unsigned p = __builtin_nontemporal_load(&prev[(size_t)node * 64 + lane]);
        rx += b * bflo(p);
        ry += b * bfhi(p);
    }
    __builtin_nontemporal_store(pack2bf(rx, ry), &out[(size_t)node * 64 + lane]);
}

// ---------------- layer-1 dense (K=12 tiny GEMM), bf16 out + fused BN stats ----------------

__global__ __launch_bounds__(256) void k_gemm1(const float* __restrict__ x, const float* __restrict__ t1,
                                               const float* __restrict__ t2, const float* __restrict__ t3,
                                               const float* __restrict__ W, const float* __restrict__ b,
                                               unsigned short* __restrict__ OUT, float* __restrict__ S,
                                               int npb, int N) {
    __shared__ float Wl[12 * 128];
    __shared__ float bl[128];
    __shared__ float sS[256];
    int tid = threadIdx.x;
    for (int i = tid; i < 1536; i += 256) Wl[i] = W[i];
    if (tid < 128) bl[tid] = b[tid];
    if (tid < 256) sS[tid] = 0.f;
    __syncthreads();
    int f = tid & 127;
    int base = blockIdx.x * npb;
    int end = base + npb < N ? base + npb : N;
    const float* rows[4] = {x, t1, t2, t3};
    float s1 = 0.f, s2 = 0.f;
    for (int node = base + (tid >> 7); node < end; node += 2) {
        float acc = bl[f];
        #pragma unroll
        for (int k = 0; k < 4; ++k) {
            float4 rv = *(const float4*)(rows[k] + (size_t)node * 4);
            acc += rv.x * Wl[(k * 3 + 0) * 128 + f];
            acc += rv.y * Wl[(k * 3 + 1) * 128 + f];
            acc += rv.z * Wl[(k * 3 + 2) * 128 + f];
        }
        unsigned short h = (unsigned short)f2bf(acc);
        OUT[(size_t)node * 128 + f] = h;
        float u = actf(bf2f(h), 0);  // leaky
        s1 += u;
        s2 += u * u;
    }
    atomicAdd(&sS[f], s1);
    atomicAdd(&sS[f + 128], s2);
    __syncthreads();
    if (tid < 256) atomicAdd(&S[tid], sS[tid]);
}

// ---------------- big GEMM: OUT[M,128] = [T0|T1|T2|T3][M,512] @ Wp[512,128] + b ----------------

// pack all 3 layers' W (each [4,128,128] fp32) into bf16 B-fragment order
__global__ __launch_bounds__(256) void k_packW(const float* __restrict__ WA, const float* __restrict__ WB,
                                               const float* __restrict__ WC, short* __restrict__ Wp) {
    int gid = blockIdx.x * 256 + threadIdx.x;  // 0..196607
    int L = gid >> 16;
    int idx = gid & 65535;
    int j = idx & 7;
    int lane = (idx >> 3) & 63;
    int rest = idx >> 9;
    int nt = rest & 7;
    int ks = rest >> 3;
    int kk = ks * 32 + (lane >> 4) * 8 + j;
    int c = nt * 16 + (lane & 15);
    const float* W = (L == 0) ? WA : (L == 1) ? WB : WC;
    Wp[gid] = f2bf(W[(size_t)(kk >> 7) * 16384 + (kk & 127) * 128 + c]);
}

// Weight-resident persistent GEMM (1 block/CU, full 128KB weight in LDS).
// doStats: fused BN stats -> S. doFinal: fused L2-normalize + 128->3 projection
// (skips OUT store, writes fout[N,3]).
__global__ __launch_bounds__(512) void k_gemm512(const short* __restrict__ T0, const short* __restrict__ T1,
                                                 const short* __restrict__ T2, const short* __restrict__ T3,
                                                 const short* __restrict__ Wp, const float* __restrict__ bias,
                                                 unsigned short* __restrict__ OUT, float* __restrict__ S,
                                                 const float* __restrict__ Wrep, const float* __restrict__ brep,
                                                 float* __restrict__ fout,
                                                 int M, int doStats, int doFinal, int act) {
    __shared__ short Wlds[65536];   // 128 KB
    __shared__ float sS[256];
    __shared__ float sW[388];       // Wrep (384) + brep (3)
    int tid = threadIdx.x;
    int lane = tid & 63, wave = tid >> 6;
    if (tid < 256) sS[tid] = 0.f;
    if (doFinal) {
        for (int i = tid; i < 384; i += 512) sW[i] = Wrep[i];
        if (tid < 3) sW[384 + tid] = brep[tid];
    }
    for (int i = tid; i < 8192; i += 512) ((int4*)Wlds)[i] = ((const int4*)Wp)[i];
    __syncthreads();

    int quad = lane >> 4;
    int col0 = lane & 15;
    const short* Ts[4] = {T0, T1, T2, T3};
    float s1[8], s2[8];
    #pragma unroll
    for (int i = 0; i < 8; ++i) { s1[i] = 0.f; s2[i] = 0.f; }

    int nt32 = (M + 31) / 32;
    int stride = gridDim.x * 8;
    for (int t = blockIdx.x * 8 + wave; t < nt32; t += stride) {
        int r0 = t * 32;
        int rowa = r0 + col0;
        int rowb = rowa + 16;
        size_t rb0 = (size_t)(rowa < M ? rowa : M - 1) * 128;
        size_t rb1 = (size_t)(rowb < M ? rowb : M - 1) * 128;
        floatx4 acc0[8], acc1[8];
        #pragma unroll
        for (int i = 0; i < 8; ++i) {
            acc0[i][0] = 0.f; acc0[i][1] = 0.f; acc0[i][2] = 0.f; acc0[i][3] = 0.f;
            acc1[i][0] = 0.f; acc1[i][1] = 0.f; acc1[i][2] = 0.f; acc1[i][3] = 0.f;
        }
        #pragma unroll 4
        for (int ks = 0; ks < 16; ++ks) {
            const short* Tm = Ts[ks >> 2];
            int aoff = (ks & 3) * 32 + quad * 8;
            short8 af0 = *((const short8*)(Tm + rb0 + aoff));
            short8 af1 = *((const short8*)(Tm + rb1 + aoff));
            #pragma unroll
            for (int nt = 0; nt < 8; ++nt) {
                short8 bf = *((const short8*)(Wlds + ((ks * 8 + nt) * 64 + lane) * 8));
                acc0[nt] = __builtin_amdgcn_mfma_f32_16x16x32_bf16(af0, bf, acc0[nt], 0, 0, 0);
                acc1[nt] = __builtin_amdgcn_mfma_f32_16x16x32_bf16(af1, bf, acc1[nt], 0, 0, 0);
            }
        }
        // C/D layout: col = lane&15, row = quad*4 + reg
        if (doFinal) {
            #pragma unroll
            for (int half = 0; half < 2; ++half) {
                #pragma unroll
                for (int rg = 0; rg < 4; ++rg) {
                    int r = r0 + half * 16 + quad * 4 + rg;
                    float sq = 0.f, p0 = 0.f, p1 = 0.f, p2 = 0.f;
                    #pragma unroll
                    for (int nt = 0; nt < 8; ++nt) {
                        int c = nt * 16 + col0;
                        float v = (half ? acc1[nt][rg] : acc0[nt][rg]) + bias[c];
                        sq += v * v;
                        p0 += v * sW[c * 3 + 0];
                        p1 += v * sW[c * 3 + 1];
                        p2 += v * sW[c * 3 + 2];
                    }
                    #pragma unroll
                    for (int d = 1; d < 16; d <<= 1) {
                        sq += __shfl_xor(sq, d);
                        p0 += __shfl_xor(p0, d);
                        p1 += __shfl_xor(p1, d);
                        p2 += __shfl_xor(p2, d);
                    }
                    if (col0 == 0 && r < M) {
                        float inv = 1.f / fmaxf(sqrtf(sq), L2_EPS);
                        fout[r * 3 + 0] = p0 * inv + sW[384];
                        fout[r * 3 + 1] = p1 * inv + sW[385];
                        fout[r * 3 + 2] = p2 * inv + sW[386];
                    }
                }
            }
        } else {
            #pragma unroll
            for (int half = 0; half < 2; ++half) {
                int rbase = r0 + half * 16 + quad * 4;
                #pragma unroll
                for (int nt = 0; nt < 8; ++nt) {
                    int c = nt * 16 + col0;
                    float bv = bias[c];
                    #pragma unroll
                    for (int rg = 0; rg < 4; ++rg) {
                        int r = rbase + rg;
                        if (r < M) {
                            float v = (half ? acc1[nt][rg] : acc0[nt][rg]) + bv;
                            unsigned short h = (unsigned short)f2bf(v);
                            OUT[(size_t)r * 128 + c] = h;
                            float u = actf(bf2f(h), act);
                            s1[nt] += u;
                            s2[nt] += u * u;
                        }
                    }
                }
            }
        }
    }
    if (doStats) {
        #pragma unroll
        for (int nt = 0; nt < 8; ++nt) {
            int c = nt * 16 + col0;
            atomicAdd(&sS[c], s1[nt]);
            atomicAdd(&sS[c + 128], s2[nt]);
        }
        __syncthreads();
        if (tid < 256) atomicAdd(&S[tid], sS[tid]);
    }
}

// ---------------- host ----------------

extern "C" void kernel_launch(void* const* d_in, const int* in_sizes, int n_in,
                              void* d_out, int out_size, void* d_ws, size_t ws_size,
                              hipStream_t stream) {
    const int N = in_sizes[0] / 3;   // 100000
    const int E = in_sizes[1] / 2;   // 1600000

    const float* x    = (const float*)d_in[0];
    const int*   ei   = (const int*)d_in[1];
    const int* esrc = ei;
    const int* edst = ei + E;
    const float* W1 = (const float*)d_in[2];  const float* b1 = (const float*)d_in[3];
    const float* W2 = (const float*)d_in[4];  const float* b2 = (const float*)d_in[5];
    const float* W3 = (const float*)d_in[6];  const float* b3 = (const float*)d_in[7];
    const float* W4 = (const float*)d_in[8];  const float* b4 = (const float*)d_in[9];
    const float* g1 = (const float*)d_in[10]; const float* be1 = (const float*)d_in[11];
    const float* g2 = (const float*)d_in[12]; const float* be2 = (const float*)d_in[13];
    const float* g3 = (const float*)d_in[14]; const float* be3 = (const float*)d_in[15];
    const float* Wrep = (const float*)d_in[16]; const float* brep = (const float*)d_in[17];
    float* out = (float*)d_out;

    char* w = (char*)d_ws;
    size_t off = 0;
    auto alloc = [&](size_t bytes) { size_t o = off; off = (off + bytes + 255) & ~(size_t)255; return o; };
    int*   arr    = (int*)(w + alloc((size_t)N * CAP * 4));      // bucket: [count, srcs...]
    int*   cnt    = (int*)(w + alloc((size_t)N * 4));            // clamped degree
    float* dinv   = (float*)(w + alloc((size_t)N * 4));
    float* snorm  = (float*)(w + alloc((size_t)N * 4));          // sum of norms per node
    int2*  edges  = (int2*)(w + alloc((size_t)N * CAP * 8));     // padded (src,norm)
    short* Wp     = (short*)(w + alloc(3 * 65536 * 2));
    float* S      = (float*)(w + alloc(4 * 256 * 4));            // BN stats: S0..S2
    float* xp     = (float*)(w + alloc((size_t)N * 4 * 4));      // padded x [N,4]
    float* t1f    = (float*)(w + alloc((size_t)N * 4 * 4));
    float* t2f    = (float*)(w + alloc((size_t)N * 4 * 4));
    float* t3f    = (float*)(w + alloc((size_t)N * 4 * 4));
    short* T0     = (short*)(w + alloc((size_t)N * 128 * 2));    // bf16 feature bufs
    short* T1     = (short*)(w + alloc((size_t)N * 128 * 2));
    short* T2     = (short*)(w + alloc((size_t)N * 128 * 2));
    short* T3     = (short*)(w + alloc((size_t)N * 128 * 2));
    unsigned short* OUT = (unsigned short*)(w + alloc((size_t)N * 128 * 2));  // bf16

    int gE = (E + 255) / 256;
    int gN = (N + 255) / 256;
    int gW = (N + 3) / 4;            // wave-per-node kernels
    float invN = 1.f / (float)N;
    int npb = (N + 255) / 256;       // nodes per block for persistent gemm1

    // --- preprocessing: one-pass padded CSR ---
    k_zero<<<gN, 256, 0, stream>>>(arr, S, x, xp, N);
    k_fillpad<<<gE, 256, 0, stream>>>(esrc, edst, arr, E);
    k_dinv<<<gN, 256, 0, stream>>>(arr, dinv, cnt, N);
    k_norm<<<gW, 256, 0, stream>>>(arr, cnt, dinv, edges, snorm, N);
    k_packW<<<768, 256, 0, stream>>>(W2, W3, W4, Wp);

    // --- layer 1 (F_in=3, fp32, stride-4 padded) ---
    k_prop3<<<gN, 256, 0, stream>>>(xp, nullptr, t1f, cnt, edges, 1.f, 0.f, N);
    k_prop3<<<gN, 256, 0, stream>>>(t1f, xp, t2f, cnt, edges, 2.f, -1.f, N);
    k_prop3<<<gN, 256, 0, stream>>>(t2f, t1f, t3f, cnt, edges, 2.f, -1.f, N);
    k_gemm1<<<256, 256, 0, stream>>>(xp, t1f, t2f, t3f, W1, b1, OUT, S, npb, N);

    // --- layers 2..4 ---
    const float* bs[3]  = {b2, b3, b4};
    const float* gs[3]  = {g2, g3, nullptr};
    const float* bes[3] = {be2, be3, nullptr};
    // act applied to the PREVIOUS layer's output when forming T0: leaky, leaky, relu
    int actsIn[3] = {0, 0, 1};
    // act for stats on THIS layer's output: leaky (l=0), relu (l=1)
    int actsOut[3] = {0, 1, 2};

    for (int l = 0; l < 3; ++l) {
        float* Sin = S + (size_t)l * 256;        // stats of previous layer output
        float* Sout = S + (size_t)(l + 1) * 256; // stats accumulated this layer
        const float* gc = (l == 0) ? g1 : gs[l - 1];
        const float* bc = (l == 0) ? be1 : bes[l - 1];
        // prop1: gather OUT (raw), act+affine-after-sum -> T1; side write T0
        k_prop1<<<gW, 256, 0, stream>>>((const unsigned*)OUT, (unsigned*)T1, (unsigned*)T0,
                                        cnt, edges, snorm, Sin, gc, bc, actsIn[l], invN, N);
        k_prop128<<<gW, 256, 0, stream>>>((const unsigned*)T1, (const unsigned*)T0, (unsigned*)T2,
                                          cnt, edges, 2.f, -1.f, N);
        k_prop128<<<gW, 256, 0, stream>>>((const unsigned*)T2, (const unsigned*)T1, (unsigned*)T3,
                                          cnt, edges, 2.f, -1.f, N);
        k_gemm512<<<256, 512, 0, stream>>>(T0, T1, T2, T3, Wp + (size_t)l * 65536, bs[l], OUT, Sout,
                                           Wrep, brep, out, N,
                                           l < 2 ? 1 : 0, l == 2 ? 1 : 0, actsOut[l]);
    }
}